// Round 7
// baseline (208.209 us; speedup 1.0000x reference)
//
#include <hip/hip_runtime.h>
#include <hip/hip_bf16.h>

typedef __hip_bfloat16 bf16;
typedef __attribute__((ext_vector_type(8))) short bf16x8;
typedef __attribute__((ext_vector_type(4))) float f32x4;

// ---------- helpers ----------
__device__ __forceinline__ float bflo(unsigned u) { return __uint_as_float(u << 16); }
__device__ __forceinline__ float bfhi(unsigned u) { return __uint_as_float(u & 0xffff0000u); }
__device__ __forceinline__ bool probe_f32(const void* mask) {
  return *(const unsigned*)mask == 0x3F800000u;
}
__device__ __forceinline__ float ldin(const void* p, size_t i, bool f32) {
  return f32 ? ((const float*)p)[i] : (float)((const bf16*)p)[i];
}

// Fragment-major pack layout (global): for global row g (0..3071), col k (0..511):
//   chunk = g>>6 (64-row chunk, 65536 B each), r = g&63, c = k>>3 (16B block)
//   byte off = chunk*65536 + (c>>2)*4096 + (r>>4)*1024 + ((c&3)*16 + (r&15))*16 + (k&7)*2

// ---------- 1. prologue: pack_w (fragment-major) + biases + spike rotation ----------
__global__ __launch_bounds__(256) void prologue(
    const void* w0, const void* w1, const void* w2, const void* w3,
    const void* w4, const void* w5,
    const void* b0, const void* b1, const void* b2, const void* b3,
    const void* b4, const void* b5, const void* g_, const void* be,
    const void* q, const void* spike, const void* theta_logit, const void* mask,
    bf16* __restrict__ Wall, float* __restrict__ biasF,
    bf16* __restrict__ q_rot, float* __restrict__ qn) {
  bool f32 = probe_f32(mask);
  int blk = blockIdx.x, t = threadIdx.x;
  if (blk < 1536) {
    int E = blk * 1024 + t * 4;
    int g = E >> 9;            // global packed row 0..3071
    int wi = g >> 9;           // matrix index 0..5
    int o = g & 511;           // row within matrix
    int k0 = E & 511;          // col (multiple of 4)
    const void* src = wi == 0 ? w0 : wi == 1 ? w1 : wi == 2 ? w2 : wi == 3 ? w3 : wi == 4 ? w4 : w5;
    int ro = o >> 7, a = o & 127, co = k0 >> 7;
    int comp = ro ^ co;                                   // Hamilton component index
    float sgn = ((0x284Eu >> (ro * 4 + co)) & 1u) ? -1.0f : 1.0f;  // Hamilton sign
    bf16 ov[4];
    #pragma unroll
    for (int j = 0; j < 4; ++j) {
      int b2 = (k0 & 127) + j;
      ov[j] = (bf16)(ldin(src, comp * 16384 + a * 128 + b2, f32) * sgn);
    }
    int r = g & 63, c = k0 >> 3;
    size_t off = (size_t)(g >> 6) * 65536 + (size_t)((c >> 2) * 4096 + (r >> 4) * 1024
               + ((c & 3) * 16 + (r & 15)) * 16 + (k0 & 7) * 2);
    *(uint2*)((char*)Wall + off) = *(const uint2*)ov;
  } else if (blk < 1544) {
    int b = blk - 1536;
    const void* src = b == 0 ? b0 : b == 1 ? b1 : b == 2 ? b2 : b == 3 ? b3
                    : b == 4 ? b4 : b == 5 ? b5 : b == 6 ? g_ : be;
    biasF[b * 512 + t] = ldin(src, t, f32);
    biasF[b * 512 + 256 + t] = ldin(src, 256 + t, f32);
  } else {
    int row = (blk - 1544) * 2 + (t >> 7);
    int l = t & 127;
    float tl = ldin(theta_logit, 0, f32);
    float tmax = 1.5707963267948966f / (1.0f + __expf(-tl));
    float th = tmax * ldin(spike, row, f32);
    float c = cosf(th), s = sinf(th);
    size_t base = (size_t)row * 512;
    float a = ldin(q, base + l, f32), b = ldin(q, base + 128 + l, f32);
    float cc = ldin(q, base + 256 + l, f32), d = ldin(q, base + 384 + l, f32);
    float r0 = c * a - s * d;
    float r1 = c * b - s * cc;
    float r2 = c * cc + s * b;
    float r3 = c * d + s * a;
    bf16* orow = q_rot + base;
    orow[l] = (bf16)r0; orow[128 + l] = (bf16)r1; orow[256 + l] = (bf16)r2; orow[384 + l] = (bf16)r3;
    qn[(size_t)row * 128 + l] = r0 * r0 + r1 * r1 + r2 * r2 + r3 * r3;
  }
}

// ---------- staging: straight coalesced 64KB copy (Wall already fragment-major) ----------
__device__ __forceinline__ void stage_B64(const bf16* __restrict__ Bw, int n0, char* Bs, int t) {
  const char* src = (const char*)Bw + (size_t)(n0 >> 6) * 65536;
  #pragma unroll
  for (int i = 0; i < 16; ++i)
    *(uint4*)(Bs + t * 16 + i * 4096) = *(const uint4*)(src + t * 16 + i * 4096);
}

// ---------- 2. FUSED dist_h + gemm1 (unchanged) ----------
__global__ __launch_bounds__(256, 2) void gemm_dist(
    const bf16* __restrict__ A, const bf16* __restrict__ Bw,
    const float* __restrict__ bias0, const float* __restrict__ bias1,
    bf16* __restrict__ MQ,
    const float* __restrict__ qn, const void* anchors, const void* lsig,
    const void* mask, float* __restrict__ h_part, float* __restrict__ pd_part) {
  __shared__ char smem[77952];
  const int t = threadIdx.x;
  if (blockIdx.x >= 128) {
    char* Bs = smem;
    const int g = blockIdx.x - 128;
    const int wave = t >> 6, lane = t & 63;
    const int quad = lane >> 4, l16 = lane & 15;
    const int m0 = (g & 31) * 256, n0 = (g >> 5) * 64;
    stage_B64(Bw, n0, Bs, t);
    __syncthreads();
    const int mbase = m0 + wave * 64;
    f32x4 acc[4][4] = {};
    bf16x8 areg[2][4], breg[2][4];
    #pragma unroll
    for (int mt = 0; mt < 4; ++mt)
      areg[0][mt] = *(const bf16x8*)(A + (size_t)(mbase + mt * 16 + l16) * 512 + quad * 8);
    #pragma unroll
    for (int nt = 0; nt < 4; ++nt)
      breg[0][nt] = *(const bf16x8*)(Bs + nt * 1024 + lane * 16);
    #pragma unroll
    for (int kk = 0; kk < 16; ++kk) {
      const int cur = kk & 1, nxt = cur ^ 1;
      if (kk < 15) {
        const int k2 = (kk + 1) * 32;
        #pragma unroll
        for (int mt = 0; mt < 4; ++mt)
          areg[nxt][mt] = *(const bf16x8*)(A + (size_t)(mbase + mt * 16 + l16) * 512 + k2 + quad * 8);
        #pragma unroll
        for (int nt = 0; nt < 4; ++nt)
          breg[nxt][nt] = *(const bf16x8*)(Bs + (kk + 1) * 4096 + nt * 1024 + lane * 16);
      }
      #pragma unroll
      for (int mt = 0; mt < 4; ++mt)
        #pragma unroll
        for (int nt = 0; nt < 4; ++nt)
          acc[mt][nt] = __builtin_amdgcn_mfma_f32_16x16x32_bf16(areg[cur][mt], breg[cur][nt],
                                                                acc[mt][nt], 0, 0, 0);
    }
    #pragma unroll
    for (int nt = 0; nt < 4; ++nt) {
      int col = n0 + nt * 16 + l16;
      float bv = col < 512 ? bias0[col] : bias1[col - 512];
      #pragma unroll
      for (int mt = 0; mt < 4; ++mt) {
        int rb = mbase + mt * 16 + quad * 4;
        #pragma unroll
        for (int r = 0; r < 4; ++r)
          MQ[(size_t)(rb + r) * 1024 + col] = (bf16)(acc[mt][nt][r] + bv);
      }
    }
  } else {
    bool f32 = probe_f32(mask);
    bf16*  qr    = (bf16*)smem;                  // 65536 B
    float* an    = (float*)(smem + 65536);       // 8192 B
    float* sIncT = (float*)(smem + 73728);       // 4096 B  [nn][k] transposed
    float* rs    = (float*)(smem + 77824);       // 64 B
    float* pd    = (float*)(smem + 77888);       // 64 B
    int bb = blockIdx.x;
    int b = bb >> 4, nc = bb & 15;
    {
      const uint4* src = (const uint4*)((const bf16*)A + ((size_t)b * 1024 + nc * 64) * 512);
      uint4* dst = (uint4*)qr;
      #pragma unroll
      for (int i = 0; i < 16; ++i) dst[t + i * 256] = src[t + i * 256];
    }
    for (int i = t; i < 2048; i += 256) {
      int k = i >> 7, l = i & 127;
      float a0 = ldin(anchors, k * 512 + l, f32);
      float a1 = ldin(anchors, k * 512 + 128 + l, f32);
      float a2 = ldin(anchors, k * 512 + 256 + l, f32);
      float a3 = ldin(anchors, k * 512 + 384 + l, f32);
      an[i] = a0 * a0 + a1 * a1 + a2 * a2 + a3 * a3;
    }
    if (t < 16) {
      float ls = ldin(lsig, t, f32);
      float ssq = __expf(ls); ssq = fmaxf(ssq * ssq, 1e-6f);
      rs[t] = -1.0f / ssq;
      pd[t] = 0.0f;
    }
    __syncthreads();
    {
      int rl = t >> 2, part = t & 3;
      int n = nc * 64 + rl;
      const float* qrow = qn + ((size_t)b * 1024 + n) * 128 + part * 32;
      f32x4 q4[8];
      #pragma unroll
      for (int i = 0; i < 8; ++i) q4[i] = *(const f32x4*)(qrow + i * 4);
      float sc[16] = {};
      #pragma unroll
      for (int i = 0; i < 8; ++i) {
        #pragma unroll
        for (int k = 0; k < 16; ++k) {
          f32x4 av = *(const f32x4*)(an + k * 128 + part * 32 + i * 4);
          sc[k] += q4[i][0] * av[0] + q4[i][1] * av[1] + q4[i][2] * av[2] + q4[i][3] * av[3];
        }
      }
      #pragma unroll
      for (int k = 0; k < 16; ++k) {
        sc[k] += __shfl_xor(sc[k], 1, 64);
        sc[k] += __shfl_xor(sc[k], 2, 64);
      }
      if (part == 0) {
        float mval = ldin(mask, b * 1024 + n, f32);
        #pragma unroll
        for (int k = 0; k < 16; ++k) {
          float inc = __expf(sc[k] * rs[k]) * mval;
          sIncT[rl * 16 + k] = inc;           // transposed: [nn][k]
          atomicAdd(&pd[k], inc);
        }
      }
    }
    __syncthreads();
    {
      float acc0[16] = {}, acc1[16] = {};
      for (int nn = 0; nn < 64; ++nn) {
        unsigned u = *(const unsigned*)(qr + nn * 512 + 2 * t);
        float v0 = bflo(u);
        float v1 = bfhi(u);
        f32x4 p0 = *(const f32x4*)(sIncT + nn * 16);
        f32x4 p1 = *(const f32x4*)(sIncT + nn * 16 + 4);
        f32x4 p2 = *(const f32x4*)(sIncT + nn * 16 + 8);
        f32x4 p3 = *(const f32x4*)(sIncT + nn * 16 + 12);
        #pragma unroll
        for (int j = 0; j < 4; ++j) {
          acc0[j]      += p0[j] * v0; acc1[j]      += p0[j] * v1;
          acc0[4 + j]  += p1[j] * v0; acc1[4 + j]  += p1[j] * v1;
          acc0[8 + j]  += p2[j] * v0; acc1[8 + j]  += p2[j] * v1;
          acc0[12 + j] += p3[j] * v0; acc1[12 + j] += p3[j] * v1;
        }
      }
      #pragma unroll
      for (int k = 0; k < 16; ++k) {
        size_t base = ((size_t)(b * 16 + k) * 16 + nc) * 512;
        float2 o2 = {acc0[k], acc1[k]};
        *(float2*)(h_part + base + 2 * t) = o2;
      }
    }
    if (t < 16) pd_part[((size_t)(b * 16 + t)) * 16 + nc] = pd[t];
  }
}

// ---------- partial row-dot against fragment-major packed W (8 of 16 col-chunks) ----------
__device__ __forceinline__ float dotW8(const char* WallB, int gRow, const float* xp512, int c4lo) {
  const char* p = WallB + (size_t)(gRow >> 6) * 65536
                + (size_t)(((gRow >> 4) & 3) * 1024 + (gRow & 15) * 16);
  float acc = 0.0f;
  #pragma unroll
  for (int c4 = c4lo; c4 < c4lo + 8; ++c4) {
    #pragma unroll
    for (int cl = 0; cl < 4; ++cl) {
      uint4 u = *(const uint4*)(p + c4 * 4096 + cl * 256);
      const float* xp = xp512 + c4 * 32 + cl * 8;
      acc += xp[0] * bflo(u.x) + xp[1] * bfhi(u.x)
           + xp[2] * bflo(u.y) + xp[3] * bfhi(u.y)
           + xp[4] * bflo(u.z) + xp[5] * bfhi(u.z)
           + xp[6] * bflo(u.w) + xp[7] * bfhi(u.w);
    }
  }
  return acc;
}

// ---------- 3. fused reduce + aggr + K/V in ONE kernel: grid 128 x 1024 ----------
// Per block = one aggregate row. reduce -> xs (LDS) -> aggr -> ys (LDS) -> K/V.
// Each output split across 2 lanes (256-MAC chains), shuffle-combined.
__global__ __launch_bounds__(1024) void akv_k(
    const float* __restrict__ h_part, const float* __restrict__ pd_part,
    const bf16* __restrict__ Wall, const float* __restrict__ biasF,
    float* __restrict__ Kh, float* __restrict__ Vh) {
  __shared__ float xs[512];
  __shared__ float ys[512];
  const char* WallB = (const char*)Wall;
  const float* ba = biasF + 1536;
  const float* bk = biasF + 2048;
  const float* bv = biasF + 2560;
  const int row = blockIdx.x;
  const int t = threadIdx.x;           // 0..1023
  float dsum = 0.0f;
  #pragma unroll
  for (int nc = 0; nc < 16; ++nc) dsum += pd_part[row * 16 + nc];
  float dinv = 1.0f / fmaxf(dsum, 1e-6f);
  if (t < 512) {
    float hv = 0.0f;
    #pragma unroll
    for (int nc = 0; nc < 16; ++nc) hv += h_part[(size_t)row * 8192 + nc * 512 + t];
    xs[t] = hv * dinv;
  }
  __syncthreads();
  const int o = t >> 1, part = t & 1;
  {
    float acc = dotW8(WallB, 1536 + o, xs, part * 8);   // w_aggr = matrix 3
    acc += __shfl_xor(acc, 1, 64);
    if (part == 0) ys[o] = acc + ba[o];
  }
  __syncthreads();
  {
    float ak = dotW8(WallB, 2048 + o, ys, part * 8);    // w_k = matrix 4
    float av = dotW8(WallB, 2560 + o, ys, part * 8);    // w_v = matrix 5
    ak += __shfl_xor(ak, 1, 64);
    av += __shfl_xor(av, 1, 64);
    if (part == 0) {
      Kh[(size_t)row * 512 + o] = ak + bk[o];
      Vh[(size_t)row * 512 + o] = av + bv[o];
    }
  }
}

// ---------- 4. fused attention + gemm2(Wo) + residual + quaternion LN ----------
// 32 rows/block, grid 256. Halves Wo L2 streaming vs 16-row version and
// doubles MFMA per loaded B-fragment. Softmax fully thread-local.
__global__ __launch_bounds__(256, 2) void attn_tail(
    const bf16* __restrict__ MQ, const float* __restrict__ Kh_g,
    const float* __restrict__ Vh_g, const bf16* __restrict__ Wall,
    const float* __restrict__ biasF, const void* q, const void* mask, void* out) {
  __shared__ float KV[8 * 1092];      // 34944 B; later aliased as 32KB A_lds
  __shared__ float P[32 * 132];       // 16896 B
  const bool f32 = probe_f32(mask);
  const int t = threadIdx.x;
  const int rowbase = blockIdx.x * 32;
  const int b = rowbase >> 10;
  // --- K into LDS (per-head layout, 68-float row pitch) ---
  for (int i = t; i < 8192; i += 256) {
    int k = i >> 9, d = i & 511, h = d >> 6, dd = d & 63;
    KV[h * 1092 + k * 68 + dd] = Kh_g[(size_t)b * 8192 + i];
  }
  __syncthreads();
  // --- scores + softmax: 1 thread per (row, head): r=t>>3, h=t&7 ---
  {
    const int r = t >> 3, h = t & 7;
    const int grow = rowbase + r;
    const uint4* qp = (const uint4*)(MQ + (size_t)grow * 1024 + 512 + h * 64);
    float sc[16] = {};
    #pragma unroll
    for (int c = 0; c < 4; ++c) {          // 16 d per chunk
      uint4 u0 = qp[c * 2], u1 = qp[c * 2 + 1];
      float qv[16];
      qv[0] = bflo(u0.x); qv[1] = bfhi(u0.x); qv[2] = bflo(u0.y); qv[3] = bfhi(u0.y);
      qv[4] = bflo(u0.z); qv[5] = bfhi(u0.z); qv[6] = bflo(u0.w); qv[7] = bfhi(u0.w);
      qv[8] = bflo(u1.x); qv[9] = bfhi(u1.x); qv[10] = bflo(u1.y); qv[11] = bfhi(u1.y);
      qv[12] = bflo(u1.z); qv[13] = bfhi(u1.z); qv[14] = bflo(u1.w); qv[15] = bfhi(u1.w);
      #pragma unroll
      for (int k = 0; k < 16; ++k) {
        const float* kp = KV + h * 1092 + k * 68 + c * 16;
        f32x4 k0 = *(const f32x4*)(kp);
        f32x4 k1 = *(const f32x4*)(kp + 4);
        f32x4 k2 = *(const f32x4*)(kp + 8);
        f32x4 k3 = *(const f32x4*)(kp + 12);
        sc[k] += qv[0] * k0[0] + qv[1] * k0[1] + qv[2] * k0[2] + qv[3] * k0[3]
               + qv[4] * k1[0] + qv[5] * k1[1] + qv[6] * k1[2] + qv[7] * k1[3]
               + qv[8] * k2[0] + qv[9] * k2[1] + qv[10] * k2[2] + qv[11] * k2[3]
               + qv[12] * k3[0] + qv[13] * k3[1] + qv[14] * k3[2] + qv[15] * k3[3];
      }
    }
    #pragma unroll
    for (int k = 0; k < 16; ++k) sc[k] *= 0.125f;
    float m = sc[0];
    #pragma unroll
    for (int k = 1; k < 16; ++k) m = fmaxf(m, sc[k]);
    float ssum = 0.0f;
    #pragma unroll
    for (int k = 0; k < 16; ++k) { sc[k] = __expf(sc[k] - m); ssum += sc[k]; }
    float inv = 1.0f / ssum;
    #pragma unroll
    for (int k = 0; k < 16; ++k) P[r * 132 + h * 16 + k] = sc[k] * inv;
  }
  __syncthreads();
  // --- V into LDS ---
  for (int i = t; i < 8192; i += 256) {
    int k = i >> 9, d = i & 511, h = d >> 6, dd = d & 63;
    KV[h * 1092 + k * 68 + dd] = Vh_g[(size_t)b * 8192 + i];
  }
  __syncthreads();
  // --- PV: thread (r, dg): r=t>>3, dg=t&7 owns d = dg*8..+8 per head ---
  float pv[8][8];
  {
    const int r = t >> 3, dg = t & 7;
    #pragma unroll
    for (int h = 0; h < 8; ++h) {
      float a0 = 0, a1 = 0, a2 = 0, a3 = 0, a4 = 0, a5 = 0, a6 = 0, a7 = 0;
      #pragma unroll
      for (int k = 0; k < 16; ++k) {
        float p = P[r * 132 + h * 16 + k];
        const float* vp = KV + h * 1092 + k * 68 + dg * 8;
        f32x4 v0 = *(const f32x4*)vp;
        f32x4 v1 = *(const f32x4*)(vp + 4);
        a0 += p * v0[0]; a1 += p * v0[1]; a2 += p * v0[2]; a3 += p * v0[3];
        a4 += p * v1[0]; a5 += p * v1[1]; a6 += p * v1[2]; a7 += p * v1[3];
      }
      pv[h][0] = a0; pv[h][1] = a1; pv[h][2] = a2; pv[h][3] = a3;
      pv[h][4] = a4; pv[h][5] = a5; pv[h][6] = a6; pv[h][7] = a7;
    }
  }
  __syncthreads();
  // --- fragment-major 32x512 A-tile (aliases KV, 32KB) ---
  // layout: off = (c>>2)*2048 + (r>>4)*1024 + ((c&3)*16 + (r&15))*16, c = col>>3
  char* A_lds = (char*)KV;
  {
    const int r = t >> 3, dg = t & 7;
    #pragma unroll
    for (int h = 0; h < 8; ++h) {
      int c = h * 8 + dg;
      int off = (c >> 2) * 2048 + (r >> 4) * 1024 + ((c & 3) * 16 + (r & 15)) * 16;
      bf16 ov[8];
      #pragma unroll
      for (int j = 0; j < 8; ++j) ov[j] = (bf16)pv[h][j];
      *(uint4*)(A_lds + off) = *(const uint4*)ov;
    }
  }
  __syncthreads();
  // --- gemm2: 32 rows x 512 cols; wave = quaternion component (128-col group) ---
  const int wave = t >> 6, lane = t & 63, quad = lane >> 4, l16 = lane & 15;
  const char* WallB = (const char*)Wall;
  f32x4 acc[2][8] = {};
  bf16x8 breg[2][8];
  bf16x8 areg[2][2];
  #pragma unroll
  for (int mt = 0; mt < 2; ++mt)
    areg[0][mt] = *(const bf16x8*)(A_lds + mt * 1024 + lane * 16);
  #pragma unroll
  for (int nt = 0; nt < 8; ++nt) {
    size_t cb = (size_t)(16 + wave * 2 + (nt >> 2)) * 65536;
    breg[0][nt] = *(const bf16x8*)(WallB + cb + (nt & 3) * 1024 + lane * 16);
  }
  #pragma unroll
  for (int kk = 0; kk < 16; ++kk) {
    const int cur = kk & 1, nxt = cur ^ 1;
    if (kk < 15) {
      #pragma unroll
      for (int mt = 0; mt < 2; ++mt)
        areg[nxt][mt] = *(const bf16x8*)(A_lds + (kk + 1) * 2048 + mt * 1024 + lane * 16);
      #pragma unroll
      for (int nt = 0; nt < 8; ++nt) {
        size_t cb = (size_t)(16 + wave * 2 + (nt >> 2)) * 65536;
        breg[nxt][nt] = *(const bf16x8*)(WallB + cb + (kk + 1) * 4096 + (nt & 3) * 1024 + lane * 16);
      }
    }
    #pragma unroll
    for (int mt = 0; mt < 2; ++mt)
      #pragma unroll
      for (int nt = 0; nt < 8; ++nt)
        acc[mt][nt] = __builtin_amdgcn_mfma_f32_16x16x32_bf16(areg[cur][mt], breg[cur][nt],
                                                              acc[mt][nt], 0, 0, 0);
  }
  // --- epilogue: +bias_o, +q, +msg_p(MQ), per-component LN, write out ---
  const float* biasO = biasF + 1024;
  const float* gamF = biasF + 3072;
  float s[2][4] = {}, s2[2][4] = {};
  #pragma unroll
  for (int mt = 0; mt < 2; ++mt)
    #pragma unroll
    for (int nt = 0; nt < 8; ++nt) {
      int gcol = wave * 128 + nt * 16 + l16;
      float bo = biasO[gcol];
      #pragma unroll
      for (int reg = 0; reg < 4; ++reg) {
        int grow = rowbase + mt * 16 + quad * 4 + reg;
        float qv = ldin(q, (size_t)grow * 512 + gcol, f32);
        float mp = (float)MQ[(size_t)grow * 1024 + gcol];
        float x = qv + mp + acc[mt][nt][reg] + bo;
        acc[mt][nt][reg] = x;
        s[mt][reg] += x; s2[mt][reg] += x * x;
      }
    }
  #pragma unroll
  for (int mt = 0; mt < 2; ++mt)
    #pragma unroll
    for (int reg = 0; reg < 4; ++reg) {
      #pragma unroll
      for (int off = 1; off <= 8; off <<= 1) {
        s[mt][reg]  += __shfl_xor(s[mt][reg], off, 64);
        s2[mt][reg] += __shfl_xor(s2[mt][reg], off, 64);
      }
    }
  #pragma unroll
  for (int mt = 0; mt < 2; ++mt)
    #pragma unroll
    for (int reg = 0; reg < 4; ++reg) {
      float m = s[mt][reg] * (1.0f / 128.0f);
      float rinv = rsqrtf(s2[mt][reg] * (1.0f / 128.0f) - m * m + 1e-5f);
      int grow = rowbase + mt * 16 + quad * 4 + reg;
      #pragma unroll
      for (int nt = 0; nt < 8; ++nt) {
        int gcol = wave * 128 + nt * 16 + l16;
        float y = (acc[mt][nt][reg] - m) * rinv * gamF[gcol] + gamF[512 + gcol];
        if (f32) ((float*)out)[(size_t)grow * 512 + gcol] = y;
        else     ((bf16*)out)[(size_t)grow * 512 + gcol] = (bf16)y;
      }
    }
}

// ---------- launch ----------
extern "C" void kernel_launch(void* const* d_in, const int* in_sizes, int n_in,
                              void* d_out, int out_size, void* d_ws, size_t ws_size,
                              hipStream_t stream) {
  (void)in_sizes; (void)n_in; (void)out_size; (void)ws_size;
  const void* q      = d_in[0];
  const void* spike  = d_in[1];
  const void* mask   = d_in[2];
  const void* tl     = d_in[3];
  const void* w_prim = d_in[4];
  const void* b_prim = d_in[5];
  const void* anchors= d_in[6];
  const void* lsig   = d_in[7];
  const void* w_aggr = d_in[8];
  const void* b_aggr = d_in[9];
  const void* w_q    = d_in[10];
  const void* b_q    = d_in[11];
  const void* w_k    = d_in[12];
  const void* b_k    = d_in[13];
  const void* w_v    = d_in[14];
  const void* b_v    = d_in[15];
  const void* w_o    = d_in[16];
  const void* b_o    = d_in[17];
  const void* gam    = d_in[18];
  const void* bet    = d_in[19];

  char* ws = (char*)d_ws;
  bf16*  Wall   = (bf16*)(ws + 0);            // 3,145,728 (fragment-major packed)
  bf16*  q_rot  = (bf16*)(ws + 3145728);      // 8,388,608
  float* qn     = (float*)(ws + 11534336);    // 4,194,304
  bf16*  MQ     = (bf16*)(ws + 15728640);     // 16,777,216
  float* h_part = (float*)(ws + 32505856);    // 4,194,304
  float* pd_part= (float*)(ws + 36700160);    // 8,192
  float* Kh     = (float*)(ws + 36708352);    // 262,144
  float* Vh     = (float*)(ws + 36970496);    // 262,144
  float* biasF  = (float*)(ws + 37232640);    // 16,384

  prologue<<<5640, 256, 0, stream>>>(w_prim, w_q, w_o, w_aggr, w_k, w_v,
                                     b_prim, b_q, b_o, b_aggr, b_k, b_v, gam, bet,
                                     q, spike, tl, mask, Wall, biasF, q_rot, qn);
  gemm_dist<<<640, 256, 0, stream>>>(q_rot, Wall, biasF + 0, biasF + 512, MQ,
                                     qn, anchors, lsig, mask, h_part, pd_part);
  akv_k<<<128, 1024, 0, stream>>>(h_part, pd_part, Wall, biasF, Kh, Vh);
  attn_tail<<<256, 256, 0, stream>>>(MQ, Kh, Vh, Wall, biasF, q, mask, d_out);
}

// Round 8
// 189.353 us; speedup vs baseline: 1.0996x; 1.0996x over previous
//
#include <hip/hip_runtime.h>
#include <hip/hip_bf16.h>

typedef __hip_bfloat16 bf16;
typedef __attribute__((ext_vector_type(8))) short bf16x8;
typedef __attribute__((ext_vector_type(4))) float f32x4;

// ---------- helpers ----------
__device__ __forceinline__ float bflo(unsigned u) { return __uint_as_float(u << 16); }
__device__ __forceinline__ float bfhi(unsigned u) { return __uint_as_float(u & 0xffff0000u); }
__device__ __forceinline__ bool probe_f32(const void* mask) {
  return *(const unsigned*)mask == 0x3F800000u;
}
__device__ __forceinline__ float ldin(const void* p, size_t i, bool f32) {
  return f32 ? ((const float*)p)[i] : (float)((const bf16*)p)[i];
}

// Fragment-major pack layout (global): for global row g (0..3071), col k (0..511):
//   chunk = g>>6 (64-row chunk, 65536 B each), r = g&63, c = k>>3 (16B block)
//   byte off = chunk*65536 + (c>>2)*4096 + (r>>4)*1024 + ((c&3)*16 + (r&15))*16 + (k&7)*2

// ---------- 1. prologue: pack_w + biases + spike rotation (rotation now 4-wide) ----------
__global__ __launch_bounds__(256) void prologue(
    const void* w0, const void* w1, const void* w2, const void* w3,
    const void* w4, const void* w5,
    const void* b0, const void* b1, const void* b2, const void* b3,
    const void* b4, const void* b5, const void* g_, const void* be,
    const void* q, const void* spike, const void* theta_logit, const void* mask,
    bf16* __restrict__ Wall, float* __restrict__ biasF,
    bf16* __restrict__ q_rot, float* __restrict__ qn) {
  bool f32 = probe_f32(mask);
  int blk = blockIdx.x, t = threadIdx.x;
  if (blk < 1536) {
    int E = blk * 1024 + t * 4;
    int g = E >> 9;            // global packed row 0..3071
    int wi = g >> 9;           // matrix index 0..5
    int o = g & 511;           // row within matrix
    int k0 = E & 511;          // col (multiple of 4)
    const void* src = wi == 0 ? w0 : wi == 1 ? w1 : wi == 2 ? w2 : wi == 3 ? w3 : wi == 4 ? w4 : w5;
    int ro = o >> 7, a = o & 127, co = k0 >> 7;
    int comp = ro ^ co;                                   // Hamilton component index
    float sgn = ((0x284Eu >> (ro * 4 + co)) & 1u) ? -1.0f : 1.0f;  // Hamilton sign
    bf16 ov[4];
    #pragma unroll
    for (int j = 0; j < 4; ++j) {
      int b2 = (k0 & 127) + j;
      ov[j] = (bf16)(ldin(src, comp * 16384 + a * 128 + b2, f32) * sgn);
    }
    int r = g & 63, c = k0 >> 3;
    size_t off = (size_t)(g >> 6) * 65536 + (size_t)((c >> 2) * 4096 + (r >> 4) * 1024
               + ((c & 3) * 16 + (r & 15)) * 16 + (k0 & 7) * 2);
    *(uint2*)((char*)Wall + off) = *(const uint2*)ov;
  } else if (blk < 1544) {
    int b = blk - 1536;
    const void* src = b == 0 ? b0 : b == 1 ? b1 : b == 2 ? b2 : b == 3 ? b3
                    : b == 4 ? b4 : b == 5 ? b5 : b == 6 ? g_ : be;
    biasF[b * 512 + t] = ldin(src, t, f32);
    biasF[b * 512 + 256 + t] = ldin(src, 256 + t, f32);
  } else {
    // rotation: 1024 blocks x 8 rows; each thread handles 4 consecutive elements
    // of each quaternion component (vectorized loads/stores, G13).
    int idx = blk - 1544;                 // 0..1023
    int row = idx * 8 + (t >> 5);
    int l = (t & 31) * 4;
    float tl = ldin(theta_logit, 0, f32);
    float tmax = 1.5707963267948966f / (1.0f + __expf(-tl));
    float th = tmax * ldin(spike, row, f32);
    float c = cosf(th), s = sinf(th);
    size_t base = (size_t)row * 512;
    float av[4], bv[4], cv[4], dv[4];
    if (f32) {
      const float* qp = (const float*)q + base + l;
      f32x4 va = *(const f32x4*)(qp);
      f32x4 vb = *(const f32x4*)(qp + 128);
      f32x4 vc = *(const f32x4*)(qp + 256);
      f32x4 vd = *(const f32x4*)(qp + 384);
      #pragma unroll
      for (int j = 0; j < 4; ++j) { av[j] = va[j]; bv[j] = vb[j]; cv[j] = vc[j]; dv[j] = vd[j]; }
    } else {
      const bf16* qp = (const bf16*)q + base + l;
      uint2 ua = *(const uint2*)(qp);
      uint2 ub = *(const uint2*)(qp + 128);
      uint2 uc = *(const uint2*)(qp + 256);
      uint2 ud = *(const uint2*)(qp + 384);
      av[0] = bflo(ua.x); av[1] = bfhi(ua.x); av[2] = bflo(ua.y); av[3] = bfhi(ua.y);
      bv[0] = bflo(ub.x); bv[1] = bfhi(ub.x); bv[2] = bflo(ub.y); bv[3] = bfhi(ub.y);
      cv[0] = bflo(uc.x); cv[1] = bfhi(uc.x); cv[2] = bflo(uc.y); cv[3] = bfhi(uc.y);
      dv[0] = bflo(ud.x); dv[1] = bfhi(ud.x); dv[2] = bflo(ud.y); dv[3] = bfhi(ud.y);
    }
    bf16 o0[4], o1[4], o2[4], o3[4];
    f32x4 qv;
    #pragma unroll
    for (int j = 0; j < 4; ++j) {
      float r0 = c * av[j] - s * dv[j];
      float r1 = c * bv[j] - s * cv[j];
      float r2 = c * cv[j] + s * bv[j];
      float r3 = c * dv[j] + s * av[j];
      o0[j] = (bf16)r0; o1[j] = (bf16)r1; o2[j] = (bf16)r2; o3[j] = (bf16)r3;
      qv[j] = r0 * r0 + r1 * r1 + r2 * r2 + r3 * r3;
    }
    bf16* orow = q_rot + base + l;
    *(uint2*)(orow)       = *(const uint2*)o0;
    *(uint2*)(orow + 128) = *(const uint2*)o1;
    *(uint2*)(orow + 256) = *(const uint2*)o2;
    *(uint2*)(orow + 384) = *(const uint2*)o3;
    *(f32x4*)(qn + (size_t)row * 128 + l) = qv;
  }
}

// ---------- staging: straight coalesced 64KB copy (Wall already fragment-major) ----------
__device__ __forceinline__ void stage_B64(const bf16* __restrict__ Bw, int n0, char* Bs, int t) {
  const char* src = (const char*)Bw + (size_t)(n0 >> 6) * 65536;
  #pragma unroll
  for (int i = 0; i < 16; ++i)
    *(uint4*)(Bs + t * 16 + i * 4096) = *(const uint4*)(src + t * 16 + i * 4096);
}

// ---------- 2. FUSED dist_h + gemm1 (unchanged from 189us config) ----------
__global__ __launch_bounds__(256, 2) void gemm_dist(
    const bf16* __restrict__ A, const bf16* __restrict__ Bw,
    const float* __restrict__ bias0, const float* __restrict__ bias1,
    bf16* __restrict__ MQ,
    const float* __restrict__ qn, const void* anchors, const void* lsig,
    const void* mask, float* __restrict__ h_part, float* __restrict__ pd_part) {
  __shared__ char smem[77952];
  const int t = threadIdx.x;
  if (blockIdx.x >= 128) {
    char* Bs = smem;
    const int g = blockIdx.x - 128;
    const int wave = t >> 6, lane = t & 63;
    const int quad = lane >> 4, l16 = lane & 15;
    const int m0 = (g & 31) * 256, n0 = (g >> 5) * 64;
    stage_B64(Bw, n0, Bs, t);
    __syncthreads();
    const int mbase = m0 + wave * 64;
    f32x4 acc[4][4] = {};
    bf16x8 areg[2][4], breg[2][4];
    #pragma unroll
    for (int mt = 0; mt < 4; ++mt)
      areg[0][mt] = *(const bf16x8*)(A + (size_t)(mbase + mt * 16 + l16) * 512 + quad * 8);
    #pragma unroll
    for (int nt = 0; nt < 4; ++nt)
      breg[0][nt] = *(const bf16x8*)(Bs + nt * 1024 + lane * 16);
    #pragma unroll
    for (int kk = 0; kk < 16; ++kk) {
      const int cur = kk & 1, nxt = cur ^ 1;
      if (kk < 15) {
        const int k2 = (kk + 1) * 32;
        #pragma unroll
        for (int mt = 0; mt < 4; ++mt)
          areg[nxt][mt] = *(const bf16x8*)(A + (size_t)(mbase + mt * 16 + l16) * 512 + k2 + quad * 8);
        #pragma unroll
        for (int nt = 0; nt < 4; ++nt)
          breg[nxt][nt] = *(const bf16x8*)(Bs + (kk + 1) * 4096 + nt * 1024 + lane * 16);
      }
      #pragma unroll
      for (int mt = 0; mt < 4; ++mt)
        #pragma unroll
        for (int nt = 0; nt < 4; ++nt)
          acc[mt][nt] = __builtin_amdgcn_mfma_f32_16x16x32_bf16(areg[cur][mt], breg[cur][nt],
                                                                acc[mt][nt], 0, 0, 0);
    }
    #pragma unroll
    for (int nt = 0; nt < 4; ++nt) {
      int col = n0 + nt * 16 + l16;
      float bv = col < 512 ? bias0[col] : bias1[col - 512];
      #pragma unroll
      for (int mt = 0; mt < 4; ++mt) {
        int rb = mbase + mt * 16 + quad * 4;
        #pragma unroll
        for (int r = 0; r < 4; ++r)
          MQ[(size_t)(rb + r) * 1024 + col] = (bf16)(acc[mt][nt][r] + bv);
      }
    }
  } else {
    bool f32 = probe_f32(mask);
    bf16*  qr    = (bf16*)smem;                  // 65536 B
    float* an    = (float*)(smem + 65536);       // 8192 B
    float* sIncT = (float*)(smem + 73728);       // 4096 B  [nn][k] transposed
    float* rs    = (float*)(smem + 77824);       // 64 B
    float* pd    = (float*)(smem + 77888);       // 64 B
    int bb = blockIdx.x;
    int b = bb >> 4, nc = bb & 15;
    {
      const uint4* src = (const uint4*)((const bf16*)A + ((size_t)b * 1024 + nc * 64) * 512);
      uint4* dst = (uint4*)qr;
      #pragma unroll
      for (int i = 0; i < 16; ++i) dst[t + i * 256] = src[t + i * 256];
    }
    for (int i = t; i < 2048; i += 256) {
      int k = i >> 7, l = i & 127;
      float a0 = ldin(anchors, k * 512 + l, f32);
      float a1 = ldin(anchors, k * 512 + 128 + l, f32);
      float a2 = ldin(anchors, k * 512 + 256 + l, f32);
      float a3 = ldin(anchors, k * 512 + 384 + l, f32);
      an[i] = a0 * a0 + a1 * a1 + a2 * a2 + a3 * a3;
    }
    if (t < 16) {
      float ls = ldin(lsig, t, f32);
      float ssq = __expf(ls); ssq = fmaxf(ssq * ssq, 1e-6f);
      rs[t] = -1.0f / ssq;
      pd[t] = 0.0f;
    }
    __syncthreads();
    {
      int rl = t >> 2, part = t & 3;
      int n = nc * 64 + rl;
      const float* qrow = qn + ((size_t)b * 1024 + n) * 128 + part * 32;
      f32x4 q4[8];
      #pragma unroll
      for (int i = 0; i < 8; ++i) q4[i] = *(const f32x4*)(qrow + i * 4);
      float sc[16] = {};
      #pragma unroll
      for (int i = 0; i < 8; ++i) {
        #pragma unroll
        for (int k = 0; k < 16; ++k) {
          f32x4 av = *(const f32x4*)(an + k * 128 + part * 32 + i * 4);
          sc[k] += q4[i][0] * av[0] + q4[i][1] * av[1] + q4[i][2] * av[2] + q4[i][3] * av[3];
        }
      }
      #pragma unroll
      for (int k = 0; k < 16; ++k) {
        sc[k] += __shfl_xor(sc[k], 1, 64);
        sc[k] += __shfl_xor(sc[k], 2, 64);
      }
      if (part == 0) {
        float mval = ldin(mask, b * 1024 + n, f32);
        #pragma unroll
        for (int k = 0; k < 16; ++k) {
          float inc = __expf(sc[k] * rs[k]) * mval;
          sIncT[rl * 16 + k] = inc;           // transposed: [nn][k]
          atomicAdd(&pd[k], inc);
        }
      }
    }
    __syncthreads();
    {
      float acc0[16] = {}, acc1[16] = {};
      for (int nn = 0; nn < 64; ++nn) {
        unsigned u = *(const unsigned*)(qr + nn * 512 + 2 * t);
        float v0 = bflo(u);
        float v1 = bfhi(u);
        f32x4 p0 = *(const f32x4*)(sIncT + nn * 16);
        f32x4 p1 = *(const f32x4*)(sIncT + nn * 16 + 4);
        f32x4 p2 = *(const f32x4*)(sIncT + nn * 16 + 8);
        f32x4 p3 = *(const f32x4*)(sIncT + nn * 16 + 12);
        #pragma unroll
        for (int j = 0; j < 4; ++j) {
          acc0[j]      += p0[j] * v0; acc1[j]      += p0[j] * v1;
          acc0[4 + j]  += p1[j] * v0; acc1[4 + j]  += p1[j] * v1;
          acc0[8 + j]  += p2[j] * v0; acc1[8 + j]  += p2[j] * v1;
          acc0[12 + j] += p3[j] * v0; acc1[12 + j] += p3[j] * v1;
        }
      }
      #pragma unroll
      for (int k = 0; k < 16; ++k) {
        size_t base = ((size_t)(b * 16 + k) * 16 + nc) * 512;
        float2 o2 = {acc0[k], acc1[k]};
        *(float2*)(h_part + base + 2 * t) = o2;
      }
    }
    if (t < 16) pd_part[((size_t)(b * 16 + t)) * 16 + nc] = pd[t];
  }
}

// ---------- partial row-dot against fragment-major packed W (4 of 16 col-chunks) ----------
__device__ __forceinline__ float dotW4(const char* WallB, int gRow, const float* xp512, int c4lo) {
  const char* p = WallB + (size_t)(gRow >> 6) * 65536
                + (size_t)(((gRow >> 4) & 3) * 1024 + (gRow & 15) * 16);
  float acc = 0.0f;
  #pragma unroll
  for (int c4 = c4lo; c4 < c4lo + 4; ++c4) {
    #pragma unroll
    for (int cl = 0; cl < 4; ++cl) {
      uint4 u = *(const uint4*)(p + c4 * 4096 + cl * 256);
      const float* xp = xp512 + c4 * 32 + cl * 8;
      acc += xp[0] * bflo(u.x) + xp[1] * bfhi(u.x)
           + xp[2] * bflo(u.y) + xp[3] * bfhi(u.y)
           + xp[4] * bflo(u.z) + xp[5] * bfhi(u.z)
           + xp[6] * bflo(u.w) + xp[7] * bfhi(u.w);
    }
  }
  return acc;
}

// ---------- 3a. reduce + aggr projection: grid 1024 (known-good R4/R6 version) ----------
__global__ __launch_bounds__(256) void aggr_k(
    const float* __restrict__ h_part, const float* __restrict__ pd_part,
    const bf16* __restrict__ Wall, const float* __restrict__ biasF,
    float* __restrict__ h_aggr) {
  __shared__ float xs[512];
  const char* WallB = (const char*)Wall;
  const float* ba = biasF + 1536;
  const int gy = blockIdx.x >> 7, row = blockIdx.x & 127;
  const int t = threadIdx.x;
  float dsum = 0.0f;
  #pragma unroll
  for (int nc = 0; nc < 16; ++nc) dsum += pd_part[row * 16 + nc];
  float dinv = 1.0f / fmaxf(dsum, 1e-6f);
  #pragma unroll
  for (int j = 0; j < 2; ++j) {
    int d = j * 256 + t;
    float hv = 0.0f;
    #pragma unroll
    for (int nc = 0; nc < 16; ++nc) hv += h_part[(size_t)row * 8192 + nc * 512 + d];
    xs[d] = hv * dinv;
  }
  __syncthreads();
  const int o = gy * 64 + (t >> 2), part = t & 3;
  float acc = dotW4(WallB, 1536 + o, xs, part * 4);
  acc += __shfl_xor(acc, 1, 64);
  acc += __shfl_xor(acc, 2, 64);
  if (part == 0) h_aggr[(size_t)row * 512 + o] = acc + ba[o];
}

// ---------- 3b. K/V projections: grid 1024 (known-good R4/R6 version) ----------
__global__ __launch_bounds__(256) void kv_k(
    const float* __restrict__ h_aggr, const bf16* __restrict__ Wall,
    const float* __restrict__ biasF,
    float* __restrict__ Kh, float* __restrict__ Vh) {
  __shared__ float ys[512];
  const char* WallB = (const char*)Wall;
  const float* bk = biasF + 2048;
  const float* bv = biasF + 2560;
  const int gy = blockIdx.x >> 7, row = blockIdx.x & 127;
  const int t = threadIdx.x;
  #pragma unroll
  for (int j = 0; j < 2; ++j) {
    int d = j * 256 + t;
    ys[d] = h_aggr[(size_t)row * 512 + d];
  }
  __syncthreads();
  const int o = gy * 64 + (t >> 2), part = t & 3;
  float ak = dotW4(WallB, 2048 + o, ys, part * 4);
  float av = dotW4(WallB, 2560 + o, ys, part * 4);
  ak += __shfl_xor(ak, 1, 64);
  ak += __shfl_xor(ak, 2, 64);
  av += __shfl_xor(av, 1, 64);
  av += __shfl_xor(av, 2, 64);
  if (part == 0) {
    Kh[(size_t)row * 512 + o] = ak + bk[o];
    Vh[(size_t)row * 512 + o] = av + bv[o];
  }
}

// ---------- 4. fused attention + gemm2(Wo) + residual + LN (known-good 16-row, grid 512) ----------
__global__ __launch_bounds__(256, 2) void attn_tail(
    const bf16* __restrict__ MQ, const float* __restrict__ Kh_g,
    const float* __restrict__ Vh_g, const bf16* __restrict__ Wall,
    const float* __restrict__ biasF, const void* q, const void* mask, void* out) {
  __shared__ float KV[8 * 1092];      // 34944 B; later aliased as 16KB A_lds
  __shared__ float P[16 * 132];       // 8448 B
  const bool f32 = probe_f32(mask);
  const int t = threadIdx.x;
  const int rowbase = blockIdx.x * 16;
  const int b = rowbase >> 10;
  for (int i = t; i < 8192; i += 256) {
    int k = i >> 9, d = i & 511, h = d >> 6, dd = d & 63;
    KV[h * 1092 + k * 68 + dd] = Kh_g[(size_t)b * 8192 + i];
  }
  __syncthreads();
  {
    const int r = t >> 4, h = (t >> 1) & 7, hf = t & 1;
    const int grow = rowbase + r;
    const uint4* qp = (const uint4*)(MQ + (size_t)grow * 1024 + 512 + h * 64 + hf * 32);
    float qv[32];
    #pragma unroll
    for (int i = 0; i < 4; ++i) {
      uint4 u = qp[i];
      qv[i * 8 + 0] = bflo(u.x); qv[i * 8 + 1] = bfhi(u.x);
      qv[i * 8 + 2] = bflo(u.y); qv[i * 8 + 3] = bfhi(u.y);
      qv[i * 8 + 4] = bflo(u.z); qv[i * 8 + 5] = bfhi(u.z);
      qv[i * 8 + 6] = bflo(u.w); qv[i * 8 + 7] = bfhi(u.w);
    }
    float sc[16];
    #pragma unroll
    for (int k = 0; k < 16; ++k) {
      float s = 0.0f;
      #pragma unroll
      for (int d4 = 0; d4 < 8; ++d4) {
        f32x4 kv = *(const f32x4*)(KV + h * 1092 + k * 68 + hf * 32 + d4 * 4);
        s += qv[d4 * 4 + 0] * kv[0] + qv[d4 * 4 + 1] * kv[1]
           + qv[d4 * 4 + 2] * kv[2] + qv[d4 * 4 + 3] * kv[3];
      }
      sc[k] = s;
    }
    #pragma unroll
    for (int k = 0; k < 16; ++k) sc[k] += __shfl_xor(sc[k], 1, 64);
    if (hf == 0) {
      #pragma unroll
      for (int k = 0; k < 16; ++k) sc[k] *= 0.125f;
      float m = sc[0];
      #pragma unroll
      for (int k = 1; k < 16; ++k) m = fmaxf(m, sc[k]);
      float ssum = 0.0f;
      #pragma unroll
      for (int k = 0; k < 16; ++k) { sc[k] = __expf(sc[k] - m); ssum += sc[k]; }
      float inv = 1.0f / ssum;
      #pragma unroll
      for (int k = 0; k < 16; ++k) P[r * 132 + h * 16 + k] = sc[k] * inv;
    }
  }
  __syncthreads();
  for (int i = t; i < 8192; i += 256) {
    int k = i >> 9, d = i & 511, h = d >> 6, dd = d & 63;
    KV[h * 1092 + k * 68 + dd] = Vh_g[(size_t)b * 8192 + i];
  }
  __syncthreads();
  float pv[8][4];
  {
    const int r = t >> 4, dg = t & 15;
    #pragma unroll
    for (int h = 0; h < 8; ++h) {
      float a0 = 0, a1 = 0, a2 = 0, a3 = 0;
      #pragma unroll
      for (int k = 0; k < 16; ++k) {
        float p = P[r * 132 + h * 16 + k];
        f32x4 va = *(const f32x4*)(KV + h * 1092 + k * 68 + dg * 4);
        a0 += p * va[0]; a1 += p * va[1]; a2 += p * va[2]; a3 += p * va[3];
      }
      pv[h][0] = a0; pv[h][1] = a1; pv[h][2] = a2; pv[h][3] = a3;
    }
  }
  __syncthreads();
  char* A_lds = (char*)KV;
  {
    const int r = t >> 4, dg = t & 15;
    #pragma unroll
    for (int h = 0; h < 8; ++h) {
      int c0 = h * 64 + dg * 4;
      int off = (c0 >> 5) * 1024 + ((c0 >> 3) & 3) * 256 + r * 16 + (c0 & 7) * 2;
      bf16 ov[4] = {(bf16)pv[h][0], (bf16)pv[h][1], (bf16)pv[h][2], (bf16)pv[h][3]};
      *(uint2*)(A_lds + off) = *(const uint2*)ov;
    }
  }
  __syncthreads();
  const int wave = t >> 6, lane = t & 63, quad = lane >> 4, l16 = lane & 15;
  const char* WallB = (const char*)Wall;
  f32x4 acc[8] = {};
  bf16x8 breg[2][8];
  bf16x8 areg[2];
  areg[0] = *(const bf16x8*)(A_lds + quad * 256 + l16 * 16);
  #pragma unroll
  for (int nt = 0; nt < 8; ++nt) {
    size_t cb = (size_t)(16 + wave * 2 + (nt >> 2)) * 65536;
    breg[0][nt] = *(const bf16x8*)(WallB + cb + (nt & 3) * 1024 + lane * 16);
  }
  #pragma unroll
  for (int kk = 0; kk < 16; ++kk) {
    const int cur = kk & 1, nxt = cur ^ 1;
    if (kk < 15) {
      areg[nxt] = *(const bf16x8*)(A_lds + (kk + 1) * 1024 + quad * 256 + l16 * 16);
      #pragma unroll
      for (int nt = 0; nt < 8; ++nt) {
        size_t cb = (size_t)(16 + wave * 2 + (nt >> 2)) * 65536;
        breg[nxt][nt] = *(const bf16x8*)(WallB + cb + (kk + 1) * 4096 + (nt & 3) * 1024 + lane * 16);
      }
    }
    #pragma unroll
    for (int nt = 0; nt < 8; ++nt)
      acc[nt] = __builtin_amdgcn_mfma_f32_16x16x32_bf16(areg[cur], breg[cur][nt], acc[nt], 0, 0, 0);
  }
  const float* biasO = biasF + 1024;
  const float* gamF = biasF + 3072;
  float xv[8][4];
  float s[4] = {0, 0, 0, 0}, s2[4] = {0, 0, 0, 0};
  #pragma unroll
  for (int nt = 0; nt < 8; ++nt) {
    int gcol = wave * 128 + nt * 16 + l16;
    float bo = biasO[gcol];
    #pragma unroll
    for (int reg = 0; reg < 4; ++reg) {
      int grow = rowbase + quad * 4 + reg;
      float qv = ldin(q, (size_t)grow * 512 + gcol, f32);
      float mp = (float)MQ[(size_t)grow * 1024 + gcol];
      float x = qv + mp + acc[nt][reg] + bo;
      xv[nt][reg] = x;
      s[reg] += x; s2[reg] += x * x;
    }
  }
  #pragma unroll
  for (int reg = 0; reg < 4; ++reg) {
    #pragma unroll
    for (int off = 1; off <= 8; off <<= 1) {
      s[reg]  += __shfl_xor(s[reg], off, 64);
      s2[reg] += __shfl_xor(s2[reg], off, 64);
    }
  }
  #pragma unroll
  for (int reg = 0; reg < 4; ++reg) {
    float m = s[reg] * (1.0f / 128.0f);
    float rinv = rsqrtf(s2[reg] * (1.0f / 128.0f) - m * m + 1e-5f);
    int grow = rowbase + quad * 4 + reg;
    #pragma unroll
    for (int nt = 0; nt < 8; ++nt) {
      int gcol = wave * 128 + nt * 16 + l16;
      float y = (xv[nt][reg] - m) * rinv * gamF[gcol] + gamF[512 + gcol];
      if (f32) ((float*)out)[(size_t)grow * 512 + gcol] = y;
      else     ((bf16*)out)[(size_t)grow * 512 + gcol] = (bf16)y;
    }
  }
}

// ---------- launch ----------
extern "C" void kernel_launch(void* const* d_in, const int* in_sizes, int n_in,
                              void* d_out, int out_size, void* d_ws, size_t ws_size,
                              hipStream_t stream) {
  (void)in_sizes; (void)n_in; (void)out_size; (void)ws_size;
  const void* q      = d_in[0];
  const void* spike  = d_in[1];
  const void* mask   = d_in[2];
  const void* tl     = d_in[3];
  const void* w_prim = d_in[4];
  const void* b_prim = d_in[5];
  const void* anchors= d_in[6];
  const void* lsig   = d_in[7];
  const void* w_aggr = d_in[8];
  const void* b_aggr = d_in[9];
  const void* w_q    = d_in[10];
  const void* b_q    = d_in[11];
  const void* w_k    = d_in[12];
  const void* b_k    = d_in[13];
  const void* w_v    = d_in[14];
  const void* b_v    = d_in[15];
  const void* w_o    = d_in[16];
  const void* b_o    = d_in[17];
  const void* gam    = d_in[18];
  const void* bet    = d_in[19];

  char* ws = (char*)d_ws;
  bf16*  Wall   = (bf16*)(ws + 0);            // 3,145,728 (fragment-major packed)
  bf16*  q_rot  = (bf16*)(ws + 3145728);      // 8,388,608
  float* qn     = (float*)(ws + 11534336);    // 4,194,304
  bf16*  MQ     = (bf16*)(ws + 15728640);     // 16,777,216
  float* h_part = (float*)(ws + 32505856);    // 4,194,304
  float* pd_part= (float*)(ws + 36700160);    // 8,192
  float* Kh     = (float*)(ws + 36708352);    // 262,144
  float* Vh     = (float*)(ws + 36970496);    // 262,144
  float* biasF  = (float*)(ws + 37232640);    // 16,384
  float* h_aggr = (float*)(ws + 37249024);    // 262,144 (end 37,511,168)

  prologue<<<2568, 256, 0, stream>>>(w_prim, w_q, w_o, w_aggr, w_k, w_v,
                                     b_prim, b_q, b_o, b_aggr, b_k, b_v, gam, bet,
                                     q, spike, tl, mask, Wall, biasF, q_rot, qn);
  gemm_dist<<<640, 256, 0, stream>>>(q_rot, Wall, biasF + 0, biasF + 512, MQ,
                                     qn, anchors, lsig, mask, h_part, pd_part);
  aggr_k<<<1024, 256, 0, stream>>>(h_part, pd_part, Wall, biasF, h_aggr);
  kv_k<<<1024, 256, 0, stream>>>(h_aggr, Wall, biasF, Kh, Vh);
  attn_tail<<<512, 256, 0, stream>>>(MQ, Kh, Vh, Wall, biasF, q, mask, d_out);
}